// Round 10
// baseline (294.390 us; speedup 1.0000x reference)
//
#include <hip/hip_runtime.h>
#include <hip/hip_bf16.h>

#define F_IN    256
#define D_HID   64
#define H_HEADS 8
#define NC      10
#define ALPHA   0.2f

typedef __attribute__((ext_vector_type(8))) short short8;
typedef __attribute__((ext_vector_type(4))) float f32x4;
typedef __attribute__((ext_vector_type(2))) float f32x2;

// ---------- bf16 helpers ----------
__device__ __forceinline__ float bfu2f(unsigned short u) {
    union { float f; unsigned int i; } c; c.i = ((unsigned int)u) << 16; return c.f;
}
__device__ __forceinline__ unsigned short f2bfu(float f) {
    union { float f; unsigned int i; } c; c.f = f;
    unsigned int x = c.i;
    x += 0x7fffu + ((x >> 16) & 1u);   // round-to-nearest-even
    return (unsigned short)(x >> 16);
}

// ---------- inline dtype detection (f32 vs bf16 storage), wave-uniform ----------
// MUST run with ALL 64 lanes active (__ballot counts active lanes only).
__device__ __forceinline__ bool detect_f32(const void* xraw) {
    unsigned int w = ((const unsigned int*)xraw)[threadIdx.x & 63];
    unsigned int e = (w >> 7) & 0xffu;
    unsigned long long m = __ballot(e >= 140u);
    return __popcll(m) > 8;
}

// ---------- prep: weight conversions + edge histogram (+pos stash) ----------
__global__ __launch_bounds__(256) void prep_kernel(
    const void* __restrict__ x_raw,
    const void* __restrict__ Wh_raw, unsigned short* __restrict__ wh_f,
    const void* __restrict__ ah_raw, float* __restrict__ ah32,
    const void* __restrict__ Wo_raw, unsigned short* __restrict__ wob_f,
    const void* __restrict__ ao_raw, float* __restrict__ ao32,
    const int* __restrict__ esrc, int* __restrict__ counts, int* __restrict__ pos_e,
    int N, int E, int bw, int ba, int bo)
{
    int b = blockIdx.x;
    bool isf32 = detect_f32(x_raw);   // all lanes active here
    if (b < bw) {                       // W_heads [8][256][64] -> fragment-major bf16
        int i = b * 256 + threadIdx.x;
        int d = i & 63, k = (i >> 6) & 255, h = i >> 14;
        float v = isf32 ? ((const float*)Wh_raw)[i] : bfu2f(((const unsigned short*)Wh_raw)[i]);
        int ks = k >> 5, q = (k >> 3) & 3, j = k & 7;
        int c = d >> 4, m = d & 15;
        wh_f[(((h * 8 + ks) * 4 + c) << 9) + (q * 16 + m) * 8 + j] = f2bfu(v);
    } else if (b < ba) {                // a_heads -> f32 (1024)
        int i = (b - bw) * 256 + threadIdx.x;
        ah32[i] = isf32 ? ((const float*)ah_raw)[i] : bfu2f(((const unsigned short*)ah_raw)[i]);
    } else if (b < bo) {                // W_out [512,10] -> fragment-major bf16, cols padded to 16
        int i = (b - ba) * 256 + threadIdx.x;   // 0..8191 = (ks<<9) + L*8 + j
        int j = i & 7, L = (i >> 3) & 63, ks = i >> 9;
        int q = L >> 4, m = L & 15;
        int k = ks * 32 + q * 8 + j;
        float v = 0.f;
        if (m < NC)
            v = isf32 ? ((const float*)Wo_raw)[k * NC + m] : bfu2f(((const unsigned short*)Wo_raw)[k * NC + m]);
        wob_f[i] = f2bfu(v);
    } else if (b == bo) {               // a_out -> f32 (20)
        int i = threadIdx.x;
        if (i < 2 * NC)
            ao32[i] = isf32 ? ((const float*)ao_raw)[i] : bfu2f(((const unsigned short*)ao_raw)[i]);
    } else {                            // edge histogram + stash row-local position
        int e = (b - bo - 1) * 256 + threadIdx.x;
        if (e < E) {
            int s = esrc[e];
            int pos = atomicAdd(&counts[s], 1);
            pos_e[e] = pos;
        }
    }
}

// ---------- hierarchical CSR scan: 2 small parallel phases ----------
__global__ __launch_bounds__(256) void sum_kernel(
    const int* __restrict__ counts, int* __restrict__ bsum, int N)
{
    __shared__ int rs[256];
    int t = threadIdx.x;
    int base = blockIdx.x * 2048 + t * 8;
    int s = 0;
    if (base + 8 <= N) {
        int4 a = *(const int4*)(counts + base);
        int4 b = *(const int4*)(counts + base + 4);
        s = (a.x + a.y + a.z + a.w) + (b.x + b.y + b.z + b.w);
    } else {
        for (int k = 0; k < 8; ++k) if (base + k < N) s += counts[base + k];
    }
    rs[t] = s;
    __syncthreads();
    for (int off = 128; off > 0; off >>= 1) {
        if (t < off) rs[t] += rs[t + off];
        __syncthreads();
    }
    if (t == 0) bsum[blockIdx.x] = rs[0];
}

__global__ __launch_bounds__(256) void emit_kernel(
    const int* __restrict__ counts, const int* __restrict__ bsum,
    int* __restrict__ row_start, int N, int E)
{
    __shared__ int ts[256];
    int t = threadIdx.x;
    int goff = 0;
    for (int j = 0; j < blockIdx.x; ++j) goff += bsum[j];
    int base = blockIdx.x * 2048 + t * 8;
    int c[8];
    int tsum = 0;
    #pragma unroll
    for (int k = 0; k < 8; ++k) {
        c[k] = (base + k < N) ? counts[base + k] : 0;
        tsum += c[k];
    }
    ts[t] = tsum;
    __syncthreads();
    for (int off = 1; off < 256; off <<= 1) {
        int u = (t >= off) ? ts[t - off] : 0;
        __syncthreads();
        ts[t] += u;
        __syncthreads();
    }
    int run = goff + ts[t] - tsum;
    #pragma unroll
    for (int k = 0; k < 8; ++k) {
        if (base + k < N) { row_start[base + k] = run; run += c[k]; }
    }
    if (blockIdx.x == 0 && t == 0) row_start[N] = E;
}

// ---------- FUSED: CSR scatter (independent) + layer-1 MFMA GEMM ----------
// Blocks [0, nsc): scatter. Blocks [nsc, nsc+2*ngm): gemm1, 4 HEADS PER BLOCK
// (bid&1 selects head half) — doubles the gemm grid to lift occupancy from
// 37.5% cap (3 blk/CU) to 75% cap; the L2-latency-bound B-fragment loads then
// hide behind 2x the waves. x rows are read twice but come from L3 (cheap).
__global__ __launch_bounds__(256) void gemm1_scatter_kernel(
    const void* __restrict__ x_raw,            // [N,256] f32 or bf16
    const unsigned short* __restrict__ wh_f,   // fragment-major bf16
    const float* __restrict__ ah,              // [8,128] f32
    unsigned char* __restrict__ h8,            // [N,512] fp8 out
    float* __restrict__ s1s, float* __restrict__ s1d,
    const int* __restrict__ esrc, const int* __restrict__ edst,
    const int* __restrict__ row_start, const int* __restrict__ pos_e,
    int* __restrict__ csr_dst,
    int N, int E, int nsc)
{
    __shared__ unsigned char Os8[64][80];      // fp8 staging, 80 B rows (16-B aligned)

    bool isf32 = detect_f32(x_raw);            // all lanes active (kernel entry)

    if (blockIdx.x < nsc) {                    // ---- scatter part ----
        int e = blockIdx.x * 256 + threadIdx.x;
        if (e < E) {
            int s = esrc[e];
            csr_dst[row_start[s] + pos_e[e]] = edst[e];
        }
        return;
    }

    // ---- gemm1 part: 64 rows x 4 heads ----
    const int bid = blockIdx.x - nsc;
    const int t = threadIdx.x;
    const int w = t >> 6, lane = t & 63;
    const int q = lane >> 4, m = lane & 15;
    const int n0 = (bid >> 1) * 64;
    const int h0 = (bid & 1) * 4;

    int r = n0 + 16 * w + m;
    long rr = (long)(r < N ? r : N - 1);
    short8 afrag[8];
    if (isf32) {
        const float* xr = (const float*)x_raw + rr * 256;
        #pragma unroll
        for (int ks = 0; ks < 8; ++ks) {
            float4 f0 = *(const float4*)(xr + ks * 32 + q * 8);
            float4 f1 = *(const float4*)(xr + ks * 32 + q * 8 + 4);
            unsigned short u[8];
            u[0] = f2bfu(f0.x); u[1] = f2bfu(f0.y); u[2] = f2bfu(f0.z); u[3] = f2bfu(f0.w);
            u[4] = f2bfu(f1.x); u[5] = f2bfu(f1.y); u[6] = f2bfu(f1.z); u[7] = f2bfu(f1.w);
            afrag[ks] = *(const short8*)u;
        }
    } else {
        const unsigned short* xr = (const unsigned short*)x_raw + rr * 256;
        #pragma unroll
        for (int ks = 0; ks < 8; ++ks)
            afrag[ks] = *(const short8*)(xr + ks * 32 + q * 8);
    }

    #pragma unroll
    for (int hh = 0; hh < 4; ++hh) {
        const int h = h0 + hh;
        f32x4 acc[4] = {};
        const unsigned short* Bh = wh_f + (((long)h * 32) << 9);
        #pragma unroll
        for (int ks = 0; ks < 8; ++ks) {
            #pragma unroll
            for (int c = 0; c < 4; ++c) {
                short8 b = *(const short8*)(Bh + (((ks * 4 + c) << 9) + lane * 8));
                acc[c] = __builtin_amdgcn_mfma_f32_16x16x32_bf16(afrag[ks], b, acc[c], 0, 0, 0);
            }
        }

        const float* a1 = ah + h * 128;
        float a1m = a1[m], a1m16 = a1[16 + m], a1m32 = a1[32 + m], a1m48 = a1[48 + m];
        float a2m = a1[64 + m], a2m16 = a1[80 + m], a2m32 = a1[96 + m], a2m48 = a1[112 + m];
        #pragma unroll
        for (int reg = 0; reg < 4; ++reg) {
            float p1 = acc[0][reg] * a1m + acc[1][reg] * a1m16 + acc[2][reg] * a1m32 + acc[3][reg] * a1m48;
            float p2 = acc[0][reg] * a2m + acc[1][reg] * a2m16 + acc[2][reg] * a2m32 + acc[3][reg] * a2m48;
            #pragma unroll
            for (int off = 1; off < 16; off <<= 1) {
                p1 += __shfl_xor(p1, off);
                p2 += __shfl_xor(p2, off);
            }
            int row = n0 + 16 * w + q * 4 + reg;
            if (m == 0 && row < N) {
                s1s[row * 8 + h] = p1;
                s1d[row * 8 + h] = p2;
            }
        }

        // pack f32 -> fp8 pairs via lane-pair shuffle (even m packs dims m,m+1)
        #pragma unroll
        for (int c = 0; c < 4; ++c) {
            #pragma unroll
            for (int reg = 0; reg < 4; ++reg) {
                float a = acc[c][reg];
                float b = __shfl_xor(a, 1);
                if (!(m & 1)) {
                    unsigned int p = __builtin_amdgcn_cvt_pk_fp8_f32(a, b, 0u, false);
                    *(unsigned short*)&Os8[16 * w + q * 4 + reg][c * 16 + m] = (unsigned short)(p & 0xffffu);
                }
            }
        }
        // writeback: 16 rows x 64 B per wave per head
        {
            int row = lane >> 2, q4 = lane & 3;
            int rr2 = n0 + 16 * w + row;
            if (rr2 < N)
                *(uint4*)(h8 + (long)rr2 * 512 + h * 64 + q4 * 16) =
                    *(const uint4*)&Os8[16 * w + row][q4 * 16];
        }
    }
}

// ---------- layer-1 CSR gather (fp8 payload) + MFMA-batched layer-2 projection ----------
__device__ __forceinline__ void accpk(f32x2& a01, f32x2& a23, f32x2& a45, f32x2& a67,
                                      float ev, uint2 v) {
    f32x2 e = {ev, ev};
    a01 += e * __builtin_amdgcn_cvt_pk_f32_fp8(v.x, false);
    a23 += e * __builtin_amdgcn_cvt_pk_f32_fp8(v.x, true);
    a45 += e * __builtin_amdgcn_cvt_pk_f32_fp8(v.y, false);
    a67 += e * __builtin_amdgcn_cvt_pk_f32_fp8(v.y, true);
}

__global__ __launch_bounds__(256) void edge_agg1_kernel(
    const int* __restrict__ row_start, const int* __restrict__ csr_dst,
    const float* __restrict__ s1s, const float* __restrict__ s1d,
    const unsigned char* __restrict__ h8,      // [N,512] fp8
    const unsigned short* __restrict__ wob,    // [16][64][8] bf16 frag-major (Wo)
    const float* __restrict__ ao,              // [20] f32
    float* __restrict__ h2p,                   // [N,16] f32, pad=0
    float* __restrict__ s2s, float* __restrict__ s2d,
    int N)
{
    __shared__ unsigned short X[16][520];      // [node][dim] bf16, +8 pad

    int lane = threadIdx.x & 63;
    int wv = threadIdx.x >> 6;
    int n0 = blockIdx.x * 16;
    int h = lane >> 3;
    const unsigned lo8 = (unsigned)lane << 3;  // byte offset of this lane's 8 dims
    const unsigned h4  = (unsigned)h << 2;     // byte offset into s1d row
    const char* __restrict__ s1db = (const char*)s1d;

    #pragma unroll 1
    for (int nl = 0; nl < 4; ++nl) {
        int nloc = wv * 4 + nl;
        int n = n0 + nloc;
        if (n >= N) continue;
        int beg = row_start[n], end = row_start[n + 1];
        float ss = s1s[n * 8 + h];

        f32x2 a01 = {0.f, 0.f}, a23 = {0.f, 0.f}, a45 = {0.f, 0.f}, a67 = {0.f, 0.f};
        float rs = 0.f;
        int i = beg;
        for (; i + 4 <= end; i += 4) {
            int d0 = csr_dst[i], d1 = csr_dst[i + 1], d2 = csr_dst[i + 2], d3 = csr_dst[i + 3];
            float sd0 = *(const float*)(s1db + ((((unsigned)d0) << 5) | h4));
            float sd1 = *(const float*)(s1db + ((((unsigned)d1) << 5) | h4));
            float sd2 = *(const float*)(s1db + ((((unsigned)d2) << 5) | h4));
            float sd3 = *(const float*)(s1db + ((((unsigned)d3) << 5) | h4));
            uint2 w0 = *(const uint2*)(h8 + ((((unsigned)d0) << 9) | lo8));
            uint2 w1 = *(const uint2*)(h8 + ((((unsigned)d1) << 9) | lo8));
            uint2 w2 = *(const uint2*)(h8 + ((((unsigned)d2) << 9) | lo8));
            uint2 w3 = *(const uint2*)(h8 + ((((unsigned)d3) << 9) | lo8));
            float sc0 = ss + sd0, sc1 = ss + sd1, sc2 = ss + sd2, sc3 = ss + sd3;
            float ev0 = __expf(-fmaxf(sc0, ALPHA * sc0));
            float ev1 = __expf(-fmaxf(sc1, ALPHA * sc1));
            float ev2 = __expf(-fmaxf(sc2, ALPHA * sc2));
            float ev3 = __expf(-fmaxf(sc3, ALPHA * sc3));
            rs += (ev0 + ev1) + (ev2 + ev3);
            accpk(a01, a23, a45, a67, ev0, w0);
            accpk(a01, a23, a45, a67, ev1, w1);
            accpk(a01, a23, a45, a67, ev2, w2);
            accpk(a01, a23, a45, a67, ev3, w3);
        }
        for (; i < end; ++i) {
            int d = csr_dst[i];
            float sd = *(const float*)(s1db + ((((unsigned)d) << 5) | h4));
            uint2 wv4 = *(const uint2*)(h8 + ((((unsigned)d) << 9) | lo8));
            float sc = ss + sd;
            float ev = __expf(-fmaxf(sc, ALPHA * sc));
            rs += ev;
            accpk(a01, a23, a45, a67, ev, wv4);
        }
        float inv = 1.f / rs;
        float accs[8] = {a01.x, a01.y, a23.x, a23.y, a45.x, a45.y, a67.x, a67.y};
        unsigned short o[8];
        #pragma unroll
        for (int j = 0; j < 8; ++j) {
            float v = accs[j] * inv;
            v = v > 0.f ? v : __expf(v) - 1.f;   // elu -> xcat element (bf16)
            o[j] = f2bfu(v);
        }
        *(uint4*)&X[nloc][lane * 8] = *(const uint4*)o;
    }
    __syncthreads();

    if (wv == 0) {
        const int q = lane >> 4, m = lane & 15;
        f32x4 pacc = {};
        #pragma unroll
        for (int ks = 0; ks < 16; ++ks) {
            short8 a = *(const short8*)&X[m][ks * 32 + q * 8];
            short8 b = *(const short8*)(wob + (ks << 9) + lane * 8);
            pacc = __builtin_amdgcn_mfma_f32_16x16x32_bf16(a, b, pacc, 0, 0, 0);
        }
        float a1m = (m < NC) ? ao[m] : 0.f;
        float a2m = (m < NC) ? ao[NC + m] : 0.f;
        #pragma unroll
        for (int reg = 0; reg < 4; ++reg) {
            int n = n0 + q * 4 + reg;           // C row = local node
            float pv = pacc[reg];                // C col = class m (0 for m>=NC)
            if (n < N) h2p[(long)n * 16 + m] = pv;
            float p1 = pv * a1m, p2 = pv * a2m;
            #pragma unroll
            for (int off = 1; off < 16; off <<= 1) {
                p1 += __shfl_xor(p1, off);
                p2 += __shfl_xor(p2, off);
            }
            if (m == 0 && n < N) { s2s[n] = p1; s2d[n] = p2; }
        }
    }
}

// ---------- layer-2 CSR gather v2: wave/node, 8 edge slots x 8 dim-lanes ----------
__global__ __launch_bounds__(256) void edge_agg2_kernel(
    const int* __restrict__ row_start, const int* __restrict__ csr_dst,
    const float* __restrict__ h2p,             // [N,16] f32, pad=0
    const float* __restrict__ s_src2, const float* __restrict__ s_dst2,
    void* __restrict__ out, const void* __restrict__ x_raw, int N)
{
    bool isf32 = detect_f32(x_raw);   // all lanes active
    int lane = threadIdx.x & 63;
    int n = blockIdx.x * 4 + (threadIdx.x >> 6);
    if (n >= N) return;
    int c2 = lane & 7, j = lane >> 3;   // 8 edge slots x 8 class-pairs
    int beg = row_start[n], end = row_start[n + 1];
    float ss = s_src2[n];
    const char* __restrict__ h2b = (const char*)h2p;
    const char* __restrict__ sdb = (const char*)s_dst2;
    const unsigned c8 = (unsigned)c2 << 3;
    float rs = 0.f, a0 = 0.f, a1 = 0.f;
    for (int i0 = beg; i0 < end; i0 += 8) {
        int i = i0 + j;
        if (i < end) {
            int d = csr_dst[i];
            float sdv = *(const float*)(sdb + (((unsigned)d) << 2));
            float sc = ss + sdv;
            float ev = __expf(-fmaxf(sc, ALPHA * sc));
            rs += ev;
            float2 hv = *(const float2*)(h2b + ((((unsigned)d) << 6) | c8));
            a0 += ev * hv.x;
            a1 += ev * hv.y;
        }
    }
    rs += __shfl_xor(rs, 8);  rs += __shfl_xor(rs, 16);  rs += __shfl_xor(rs, 32);
    a0 += __shfl_xor(a0, 8);  a0 += __shfl_xor(a0, 16);  a0 += __shfl_xor(a0, 32);
    a1 += __shfl_xor(a1, 8);  a1 += __shfl_xor(a1, 16);  a1 += __shfl_xor(a1, 32);
    float inv = 1.f / rs;
    float v0 = a0 * inv, v1 = a1 * inv;
    v0 = v0 > 0.f ? v0 : __expf(v0) - 1.f;       // elu
    v1 = v1 > 0.f ? v1 : __expf(v1) - 1.f;
    // log-softmax over the 10 valid classes (c2<5 holds valid pairs)
    bool valid = (c2 * 2 + 1 < NC);
    float vm = valid ? fmaxf(v0, v1) : -1e30f;
    #pragma unroll
    for (int off = 1; off < 8; off <<= 1) vm = fmaxf(vm, __shfl_xor(vm, off, 64));
    float ex = valid ? (__expf(v0 - vm) + __expf(v1 - vm)) : 0.f;
    #pragma unroll
    for (int off = 1; off < 8; off <<= 1) ex += __shfl_xor(ex, off, 64);
    float lse = vm + logf(ex);
    if (valid && j == 0) {
        if (isf32) {
            *(float2*)((float*)out + (long)n * NC + c2 * 2) = make_float2(v0 - lse, v1 - lse);
        } else {
            unsigned int o = (unsigned int)f2bfu(v0 - lse) | ((unsigned int)f2bfu(v1 - lse) << 16);
            *(unsigned int*)((unsigned short*)out + (long)n * NC + c2 * 2) = o;
        }
    }
}

extern "C" void kernel_launch(void* const* d_in, const int* in_sizes, int n_in,
                              void* d_out, int out_size, void* d_ws, size_t ws_size,
                              hipStream_t stream)
{
    const void* x_raw  = d_in[0];
    const int*  esrc   = (const int*)d_in[1];
    const int*  edst   = (const int*)d_in[2];
    const void* Wh_raw = d_in[3];
    const void* ah_raw = d_in[4];
    const void* Wo_raw = d_in[5];
    const void* ao_raw = d_in[6];

    const int N = in_sizes[0] / F_IN;
    const int E = in_sizes[1];

    char* ws = (char*)d_ws;
    size_t off = 0;
    auto alloc = [&](size_t bytes) -> void* {
        void* p = ws + off;
        off = (off + bytes + 255) & ~(size_t)255;
        return p;
    };
    // zero-init region first (counts only -> ONE memset)
    int*            counts    = (int*)           alloc((size_t)N * 4);

    unsigned short* wh_f      = (unsigned short*)alloc((size_t)H_HEADS * D_HID * F_IN * 2);
    float*          ah32      = (float*)         alloc((size_t)H_HEADS * 2 * D_HID * 4);
    unsigned short* wob_f     = (unsigned short*)alloc((size_t)16 * 64 * 8 * 2);
    float*          ao32      = (float*)         alloc((size_t)2 * NC * 4);
    unsigned char*  h8        = (unsigned char*) alloc((size_t)N * 512);
    float*          s1s       = (float*)         alloc((size_t)N * 8 * 4);
    float*          s1d       = (float*)         alloc((size_t)N * 8 * 4);
    float*          h2p       = (float*)         alloc((size_t)N * 16 * 4);
    float*          s2s       = (float*)         alloc((size_t)N * 4);
    float*          s2d       = (float*)         alloc((size_t)N * 4);
    int*            row_start = (int*)           alloc((size_t)(N + 1) * 4);
    int*            csr_dst   = (int*)           alloc((size_t)E * 4);
    int*            pos_e     = (int*)           alloc((size_t)E * 4);
    int             nsb       = (N + 2047) / 2048;
    int*            bsum      = (int*)           alloc((size_t)nsb * 4);
    (void)ws_size;

    hipMemsetAsync(counts, 0, (size_t)N * 4, stream);

    // prep: weight conversions + histogram (dtype detected per-block from x sample)
    int bw = (H_HEADS * F_IN * D_HID) / 256;               // W frag blocks (512)
    int ba = bw + (H_HEADS * 2 * D_HID) / 256;             // + ah blocks (4)
    int bo = ba + (16 * 64 * 8) / 256;                     // + wob frag blocks (32); bo = ao block
    int nb = bo + 1 + (E + 255) / 256;                     // + hist blocks
    prep_kernel<<<nb, 256, 0, stream>>>(x_raw, Wh_raw, wh_f, ah_raw, ah32,
                                        Wo_raw, wob_f, ao_raw, ao32,
                                        esrc, counts, pos_e, N, E, bw, ba, bo);

    // hierarchical scan (2 dispatches)
    sum_kernel<<<nsb, 256, 0, stream>>>(counts, bsum, N);
    emit_kernel<<<nsb, 256, 0, stream>>>(counts, bsum, row_start, N, E);

    // fused scatter (independent) + layer-1 GEMM (4 heads/block, 2x grid), one dispatch
    int nsc = (E + 255) / 256;
    int ngm = (N + 63) / 64;
    gemm1_scatter_kernel<<<nsc + 2 * ngm, 256, 0, stream>>>(x_raw, wh_f, ah32, h8, s1s, s1d,
                                                            esrc, edst, row_start, pos_e, csr_dst,
                                                            N, E, nsc);

    // layer-1 aggregation with MFMA-batched layer-2 projection
    edge_agg1_kernel<<<(N + 15) / 16, 256, 0, stream>>>(row_start, csr_dst, s1s, s1d,
                                                        h8, wob_f, ao32,
                                                        h2p, s2s, s2d, N);

    // layer-2 aggregation + log-softmax
    edge_agg2_kernel<<<(N + 3) / 4, 256, 0, stream>>>(row_start, csr_dst, h2p, s2s, s2d, d_out, x_raw, N);
}

// Round 11
// 281.298 us; speedup vs baseline: 1.0465x; 1.0465x over previous
//
#include <hip/hip_runtime.h>
#include <hip/hip_bf16.h>

#define F_IN    256
#define D_HID   64
#define H_HEADS 8
#define NC      10
#define ALPHA   0.2f

typedef __attribute__((ext_vector_type(8))) short short8;
typedef __attribute__((ext_vector_type(4))) float f32x4;
typedef __attribute__((ext_vector_type(2))) float f32x2;

// ---------- bf16 helpers ----------
__device__ __forceinline__ float bfu2f(unsigned short u) {
    union { float f; unsigned int i; } c; c.i = ((unsigned int)u) << 16; return c.f;
}
__device__ __forceinline__ unsigned short f2bfu(float f) {
    union { float f; unsigned int i; } c; c.f = f;
    unsigned int x = c.i;
    x += 0x7fffu + ((x >> 16) & 1u);   // round-to-nearest-even
    return (unsigned short)(x >> 16);
}

// ---------- inline dtype detection (f32 vs bf16 storage), wave-uniform ----------
// MUST run with ALL 64 lanes active (__ballot counts active lanes only).
__device__ __forceinline__ bool detect_f32(const void* xraw) {
    unsigned int w = ((const unsigned int*)xraw)[threadIdx.x & 63];
    unsigned int e = (w >> 7) & 0xffu;
    unsigned long long m = __ballot(e >= 140u);
    return __popcll(m) > 8;
}

// ---------- prep: weight conversions + edge histogram (+pos stash) ----------
__global__ __launch_bounds__(256) void prep_kernel(
    const void* __restrict__ x_raw,
    const void* __restrict__ Wh_raw, unsigned short* __restrict__ wh_f,
    const void* __restrict__ ah_raw, float* __restrict__ ah32,
    const void* __restrict__ Wo_raw, unsigned short* __restrict__ wob_f,
    const void* __restrict__ ao_raw, float* __restrict__ ao32,
    const int* __restrict__ esrc, int* __restrict__ counts, int* __restrict__ pos_e,
    int N, int E, int bw, int ba, int bo)
{
    int b = blockIdx.x;
    bool isf32 = detect_f32(x_raw);   // all lanes active here
    if (b < bw) {                       // W_heads [8][256][64] -> fragment-major bf16
        int i = b * 256 + threadIdx.x;
        int d = i & 63, k = (i >> 6) & 255, h = i >> 14;
        float v = isf32 ? ((const float*)Wh_raw)[i] : bfu2f(((const unsigned short*)Wh_raw)[i]);
        int ks = k >> 5, q = (k >> 3) & 3, j = k & 7;
        int c = d >> 4, m = d & 15;
        wh_f[(((h * 8 + ks) * 4 + c) << 9) + (q * 16 + m) * 8 + j] = f2bfu(v);
    } else if (b < ba) {                // a_heads -> f32 (1024)
        int i = (b - bw) * 256 + threadIdx.x;
        ah32[i] = isf32 ? ((const float*)ah_raw)[i] : bfu2f(((const unsigned short*)ah_raw)[i]);
    } else if (b < bo) {                // W_out [512,10] -> fragment-major bf16, cols padded to 16
        int i = (b - ba) * 256 + threadIdx.x;   // 0..8191 = (ks<<9) + L*8 + j
        int j = i & 7, L = (i >> 3) & 63, ks = i >> 9;
        int q = L >> 4, m = L & 15;
        int k = ks * 32 + q * 8 + j;
        float v = 0.f;
        if (m < NC)
            v = isf32 ? ((const float*)Wo_raw)[k * NC + m] : bfu2f(((const unsigned short*)Wo_raw)[k * NC + m]);
        wob_f[i] = f2bfu(v);
    } else if (b == bo) {               // a_out -> f32 (20)
        int i = threadIdx.x;
        if (i < 2 * NC)
            ao32[i] = isf32 ? ((const float*)ao_raw)[i] : bfu2f(((const unsigned short*)ao_raw)[i]);
    } else {                            // edge histogram + stash row-local position
        int e = (b - bo - 1) * 256 + threadIdx.x;
        if (e < E) {
            int s = esrc[e];
            int pos = atomicAdd(&counts[s], 1);
            pos_e[e] = pos;
        }
    }
}

// ---------- hierarchical CSR scan: 2 small parallel phases ----------
__global__ __launch_bounds__(256) void sum_kernel(
    const int* __restrict__ counts, int* __restrict__ bsum, int N)
{
    __shared__ int rs[256];
    int t = threadIdx.x;
    int base = blockIdx.x * 2048 + t * 8;
    int s = 0;
    if (base + 8 <= N) {
        int4 a = *(const int4*)(counts + base);
        int4 b = *(const int4*)(counts + base + 4);
        s = (a.x + a.y + a.z + a.w) + (b.x + b.y + b.z + b.w);
    } else {
        for (int k = 0; k < 8; ++k) if (base + k < N) s += counts[base + k];
    }
    rs[t] = s;
    __syncthreads();
    for (int off = 128; off > 0; off >>= 1) {
        if (t < off) rs[t] += rs[t + off];
        __syncthreads();
    }
    if (t == 0) bsum[blockIdx.x] = rs[0];
}

__global__ __launch_bounds__(256) void emit_kernel(
    const int* __restrict__ counts, const int* __restrict__ bsum,
    int* __restrict__ row_start, int N, int E)
{
    __shared__ int ts[256];
    int t = threadIdx.x;
    int goff = 0;
    for (int j = 0; j < blockIdx.x; ++j) goff += bsum[j];
    int base = blockIdx.x * 2048 + t * 8;
    int c[8];
    int tsum = 0;
    #pragma unroll
    for (int k = 0; k < 8; ++k) {
        c[k] = (base + k < N) ? counts[base + k] : 0;
        tsum += c[k];
    }
    ts[t] = tsum;
    __syncthreads();
    for (int off = 1; off < 256; off <<= 1) {
        int u = (t >= off) ? ts[t - off] : 0;
        __syncthreads();
        ts[t] += u;
        __syncthreads();
    }
    int run = goff + ts[t] - tsum;
    #pragma unroll
    for (int k = 0; k < 8; ++k) {
        if (base + k < N) { row_start[base + k] = run; run += c[k]; }
    }
    if (blockIdx.x == 0 && t == 0) row_start[N] = E;
}

// ---------- FUSED: layer-1 MFMA GEMM (blocks first) + CSR scatter (after) ----------
// Blocks [0, ngm): gemm1 — 8 heads/block, reads x_raw directly, h stored FP8.
// Blocks [ngm, ...): scatter. GEMM blocks are dispatched FIRST so the long-pole
// waves gain residency at t=0; the short scatter blocks backfill as they retire
// (r10 showed scatter-first serializes the two phases).
__global__ __launch_bounds__(256) void gemm1_scatter_kernel(
    const void* __restrict__ x_raw,            // [N,256] f32 or bf16
    const unsigned short* __restrict__ wh_f,   // fragment-major bf16
    const float* __restrict__ ah,              // [8,128] f32
    unsigned char* __restrict__ h8,            // [N,512] fp8 out
    float* __restrict__ s1s, float* __restrict__ s1d,
    const int* __restrict__ esrc, const int* __restrict__ edst,
    const int* __restrict__ row_start, const int* __restrict__ pos_e,
    int* __restrict__ csr_dst,
    int N, int E, int ngm)
{
    __shared__ unsigned char Os8[64][80];      // fp8 staging, 80 B rows (16-B aligned)

    bool isf32 = detect_f32(x_raw);            // all lanes active (kernel entry)

    if (blockIdx.x >= ngm) {                   // ---- scatter part (dispatched last) ----
        int e = (blockIdx.x - ngm) * 256 + threadIdx.x;
        if (e < E) {
            int s = esrc[e];
            csr_dst[row_start[s] + pos_e[e]] = edst[e];
        }
        return;
    }

    // ---- gemm1 part: 64 rows x 8 heads ----
    const int t = threadIdx.x;
    const int w = t >> 6, lane = t & 63;
    const int q = lane >> 4, m = lane & 15;
    const int n0 = blockIdx.x * 64;

    int r = n0 + 16 * w + m;
    long rr = (long)(r < N ? r : N - 1);
    short8 afrag[8];
    if (isf32) {
        const float* xr = (const float*)x_raw + rr * 256;
        #pragma unroll
        for (int ks = 0; ks < 8; ++ks) {
            float4 f0 = *(const float4*)(xr + ks * 32 + q * 8);
            float4 f1 = *(const float4*)(xr + ks * 32 + q * 8 + 4);
            unsigned short u[8];
            u[0] = f2bfu(f0.x); u[1] = f2bfu(f0.y); u[2] = f2bfu(f0.z); u[3] = f2bfu(f0.w);
            u[4] = f2bfu(f1.x); u[5] = f2bfu(f1.y); u[6] = f2bfu(f1.z); u[7] = f2bfu(f1.w);
            afrag[ks] = *(const short8*)u;
        }
    } else {
        const unsigned short* xr = (const unsigned short*)x_raw + rr * 256;
        #pragma unroll
        for (int ks = 0; ks < 8; ++ks)
            afrag[ks] = *(const short8*)(xr + ks * 32 + q * 8);
    }

    #pragma unroll
    for (int h = 0; h < 8; ++h) {
        f32x4 acc[4] = {};
        const unsigned short* Bh = wh_f + (((long)h * 32) << 9);
        #pragma unroll
        for (int ks = 0; ks < 8; ++ks) {
            #pragma unroll
            for (int c = 0; c < 4; ++c) {
                short8 b = *(const short8*)(Bh + (((ks * 4 + c) << 9) + lane * 8));
                acc[c] = __builtin_amdgcn_mfma_f32_16x16x32_bf16(afrag[ks], b, acc[c], 0, 0, 0);
            }
        }

        const float* a1 = ah + h * 128;
        float a1m = a1[m], a1m16 = a1[16 + m], a1m32 = a1[32 + m], a1m48 = a1[48 + m];
        float a2m = a1[64 + m], a2m16 = a1[80 + m], a2m32 = a1[96 + m], a2m48 = a1[112 + m];
        #pragma unroll
        for (int reg = 0; reg < 4; ++reg) {
            float p1 = acc[0][reg] * a1m + acc[1][reg] * a1m16 + acc[2][reg] * a1m32 + acc[3][reg] * a1m48;
            float p2 = acc[0][reg] * a2m + acc[1][reg] * a2m16 + acc[2][reg] * a2m32 + acc[3][reg] * a2m48;
            #pragma unroll
            for (int off = 1; off < 16; off <<= 1) {
                p1 += __shfl_xor(p1, off);
                p2 += __shfl_xor(p2, off);
            }
            int row = n0 + 16 * w + q * 4 + reg;
            if (m == 0 && row < N) {
                s1s[row * 8 + h] = p1;
                s1d[row * 8 + h] = p2;
            }
        }

        // pack f32 -> fp8 pairs via lane-pair shuffle (even m packs dims m,m+1)
        #pragma unroll
        for (int c = 0; c < 4; ++c) {
            #pragma unroll
            for (int reg = 0; reg < 4; ++reg) {
                float a = acc[c][reg];
                float b = __shfl_xor(a, 1);
                if (!(m & 1)) {
                    unsigned int p = __builtin_amdgcn_cvt_pk_fp8_f32(a, b, 0u, false);
                    *(unsigned short*)&Os8[16 * w + q * 4 + reg][c * 16 + m] = (unsigned short)(p & 0xffffu);
                }
            }
        }
        // writeback: 16 rows x 64 B per wave per head
        {
            int row = lane >> 2, q4 = lane & 3;
            int rr2 = n0 + 16 * w + row;
            if (rr2 < N)
                *(uint4*)(h8 + (long)rr2 * 512 + h * 64 + q4 * 16) =
                    *(const uint4*)&Os8[16 * w + row][q4 * 16];
        }
    }
}

// ---------- layer-1 CSR gather (fp8 payload) + MFMA-batched layer-2 projection ----------
__device__ __forceinline__ void accpk(f32x2& a01, f32x2& a23, f32x2& a45, f32x2& a67,
                                      float ev, uint2 v) {
    f32x2 e = {ev, ev};
    a01 += e * __builtin_amdgcn_cvt_pk_f32_fp8(v.x, false);
    a23 += e * __builtin_amdgcn_cvt_pk_f32_fp8(v.x, true);
    a45 += e * __builtin_amdgcn_cvt_pk_f32_fp8(v.y, false);
    a67 += e * __builtin_amdgcn_cvt_pk_f32_fp8(v.y, true);
}

__global__ __launch_bounds__(256) void edge_agg1_kernel(
    const int* __restrict__ row_start, const int* __restrict__ csr_dst,
    const float* __restrict__ s1s, const float* __restrict__ s1d,
    const unsigned char* __restrict__ h8,      // [N,512] fp8
    const unsigned short* __restrict__ wob,    // [16][64][8] bf16 frag-major (Wo)
    const float* __restrict__ ao,              // [20] f32
    float* __restrict__ h2p,                   // [N,16] f32, pad=0
    float* __restrict__ s2s, float* __restrict__ s2d,
    int N)
{
    __shared__ unsigned short X[16][520];      // [node][dim] bf16, +8 pad

    int lane = threadIdx.x & 63;
    int wv = threadIdx.x >> 6;
    int n0 = blockIdx.x * 16;
    int h = lane >> 3;
    const unsigned lo8 = (unsigned)lane << 3;  // byte offset of this lane's 8 dims
    const unsigned h4  = (unsigned)h << 2;     // byte offset into s1d row
    const char* __restrict__ s1db = (const char*)s1d;

    #pragma unroll 1
    for (int nl = 0; nl < 4; ++nl) {
        int nloc = wv * 4 + nl;
        int n = n0 + nloc;
        if (n >= N) continue;
        int beg = row_start[n], end = row_start[n + 1];
        float ss = s1s[n * 8 + h];

        f32x2 a01 = {0.f, 0.f}, a23 = {0.f, 0.f}, a45 = {0.f, 0.f}, a67 = {0.f, 0.f};
        float rs = 0.f;
        int i = beg;
        for (; i + 4 <= end; i += 4) {
            int d0 = csr_dst[i], d1 = csr_dst[i + 1], d2 = csr_dst[i + 2], d3 = csr_dst[i + 3];
            float sd0 = *(const float*)(s1db + ((((unsigned)d0) << 5) | h4));
            float sd1 = *(const float*)(s1db + ((((unsigned)d1) << 5) | h4));
            float sd2 = *(const float*)(s1db + ((((unsigned)d2) << 5) | h4));
            float sd3 = *(const float*)(s1db + ((((unsigned)d3) << 5) | h4));
            uint2 w0 = *(const uint2*)(h8 + ((((unsigned)d0) << 9) | lo8));
            uint2 w1 = *(const uint2*)(h8 + ((((unsigned)d1) << 9) | lo8));
            uint2 w2 = *(const uint2*)(h8 + ((((unsigned)d2) << 9) | lo8));
            uint2 w3 = *(const uint2*)(h8 + ((((unsigned)d3) << 9) | lo8));
            float sc0 = ss + sd0, sc1 = ss + sd1, sc2 = ss + sd2, sc3 = ss + sd3;
            float ev0 = __expf(-fmaxf(sc0, ALPHA * sc0));
            float ev1 = __expf(-fmaxf(sc1, ALPHA * sc1));
            float ev2 = __expf(-fmaxf(sc2, ALPHA * sc2));
            float ev3 = __expf(-fmaxf(sc3, ALPHA * sc3));
            rs += (ev0 + ev1) + (ev2 + ev3);
            accpk(a01, a23, a45, a67, ev0, w0);
            accpk(a01, a23, a45, a67, ev1, w1);
            accpk(a01, a23, a45, a67, ev2, w2);
            accpk(a01, a23, a45, a67, ev3, w3);
        }
        for (; i < end; ++i) {
            int d = csr_dst[i];
            float sd = *(const float*)(s1db + ((((unsigned)d) << 5) | h4));
            uint2 wv4 = *(const uint2*)(h8 + ((((unsigned)d) << 9) | lo8));
            float sc = ss + sd;
            float ev = __expf(-fmaxf(sc, ALPHA * sc));
            rs += ev;
            accpk(a01, a23, a45, a67, ev, wv4);
        }
        float inv = 1.f / rs;
        float accs[8] = {a01.x, a01.y, a23.x, a23.y, a45.x, a45.y, a67.x, a67.y};
        unsigned short o[8];
        #pragma unroll
        for (int j = 0; j < 8; ++j) {
            float v = accs[j] * inv;
            v = v > 0.f ? v : __expf(v) - 1.f;   // elu -> xcat element (bf16)
            o[j] = f2bfu(v);
        }
        *(uint4*)&X[nloc][lane * 8] = *(const uint4*)o;
    }
    __syncthreads();

    if (wv == 0) {
        const int q = lane >> 4, m = lane & 15;
        f32x4 pacc = {};
        #pragma unroll
        for (int ks = 0; ks < 16; ++ks) {
            short8 a = *(const short8*)&X[m][ks * 32 + q * 8];
            short8 b = *(const short8*)(wob + (ks << 9) + lane * 8);
            pacc = __builtin_amdgcn_mfma_f32_16x16x32_bf16(a, b, pacc, 0, 0, 0);
        }
        float a1m = (m < NC) ? ao[m] : 0.f;
        float a2m = (m < NC) ? ao[NC + m] : 0.f;
        #pragma unroll
        for (int reg = 0; reg < 4; ++reg) {
            int n = n0 + q * 4 + reg;           // C row = local node
            float pv = pacc[reg];                // C col = class m (0 for m>=NC)
            if (n < N) h2p[(long)n * 16 + m] = pv;
            float p1 = pv * a1m, p2 = pv * a2m;
            #pragma unroll
            for (int off = 1; off < 16; off <<= 1) {
                p1 += __shfl_xor(p1, off);
                p2 += __shfl_xor(p2, off);
            }
            if (m == 0 && n < N) { s2s[n] = p1; s2d[n] = p2; }
        }
    }
}

// ---------- layer-2 CSR gather v2: wave/node, 8 edge slots x 8 dim-lanes ----------
__global__ __launch_bounds__(256) void edge_agg2_kernel(
    const int* __restrict__ row_start, const int* __restrict__ csr_dst,
    const float* __restrict__ h2p,             // [N,16] f32, pad=0
    const float* __restrict__ s_src2, const float* __restrict__ s_dst2,
    void* __restrict__ out, const void* __restrict__ x_raw, int N)
{
    bool isf32 = detect_f32(x_raw);   // all lanes active
    int lane = threadIdx.x & 63;
    int n = blockIdx.x * 4 + (threadIdx.x >> 6);
    if (n >= N) return;
    int c2 = lane & 7, j = lane >> 3;   // 8 edge slots x 8 class-pairs
    int beg = row_start[n], end = row_start[n + 1];
    float ss = s_src2[n];
    const char* __restrict__ h2b = (const char*)h2p;
    const char* __restrict__ sdb = (const char*)s_dst2;
    const unsigned c8 = (unsigned)c2 << 3;
    float rs = 0.f, a0 = 0.f, a1 = 0.f;
    for (int i0 = beg; i0 < end; i0 += 8) {
        int i = i0 + j;
        if (i < end) {
            int d = csr_dst[i];
            float sdv = *(const float*)(sdb + (((unsigned)d) << 2));
            float sc = ss + sdv;
            float ev = __expf(-fmaxf(sc, ALPHA * sc));
            rs += ev;
            float2 hv = *(const float2*)(h2b + ((((unsigned)d) << 6) | c8));
            a0 += ev * hv.x;
            a1 += ev * hv.y;
        }
    }
    rs += __shfl_xor(rs, 8);  rs += __shfl_xor(rs, 16);  rs += __shfl_xor(rs, 32);
    a0 += __shfl_xor(a0, 8);  a0 += __shfl_xor(a0, 16);  a0 += __shfl_xor(a0, 32);
    a1 += __shfl_xor(a1, 8);  a1 += __shfl_xor(a1, 16);  a1 += __shfl_xor(a1, 32);
    float inv = 1.f / rs;
    float v0 = a0 * inv, v1 = a1 * inv;
    v0 = v0 > 0.f ? v0 : __expf(v0) - 1.f;       // elu
    v1 = v1 > 0.f ? v1 : __expf(v1) - 1.f;
    // log-softmax over the 10 valid classes (c2<5 holds valid pairs)
    bool valid = (c2 * 2 + 1 < NC);
    float vm = valid ? fmaxf(v0, v1) : -1e30f;
    #pragma unroll
    for (int off = 1; off < 8; off <<= 1) vm = fmaxf(vm, __shfl_xor(vm, off, 64));
    float ex = valid ? (__expf(v0 - vm) + __expf(v1 - vm)) : 0.f;
    #pragma unroll
    for (int off = 1; off < 8; off <<= 1) ex += __shfl_xor(ex, off, 64);
    float lse = vm + logf(ex);
    if (valid && j == 0) {
        if (isf32) {
            *(float2*)((float*)out + (long)n * NC + c2 * 2) = make_float2(v0 - lse, v1 - lse);
        } else {
            unsigned int o = (unsigned int)f2bfu(v0 - lse) | ((unsigned int)f2bfu(v1 - lse) << 16);
            *(unsigned int*)((unsigned short*)out + (long)n * NC + c2 * 2) = o;
        }
    }
}

extern "C" void kernel_launch(void* const* d_in, const int* in_sizes, int n_in,
                              void* d_out, int out_size, void* d_ws, size_t ws_size,
                              hipStream_t stream)
{
    const void* x_raw  = d_in[0];
    const int*  esrc   = (const int*)d_in[1];
    const int*  edst   = (const int*)d_in[2];
    const void* Wh_raw = d_in[3];
    const void* ah_raw = d_in[4];
    const void* Wo_raw = d_in[5];
    const void* ao_raw = d_in[6];

    const int N = in_sizes[0] / F_IN;
    const int E = in_sizes[1];

    char* ws = (char*)d_ws;
    size_t off = 0;
    auto alloc = [&](size_t bytes) -> void* {
        void* p = ws + off;
        off = (off + bytes + 255) & ~(size_t)255;
        return p;
    };
    // zero-init region first (counts only -> ONE memset)
    int*            counts    = (int*)           alloc((size_t)N * 4);

    unsigned short* wh_f      = (unsigned short*)alloc((size_t)H_HEADS * D_HID * F_IN * 2);
    float*          ah32      = (float*)         alloc((size_t)H_HEADS * 2 * D_HID * 4);
    unsigned short* wob_f     = (unsigned short*)alloc((size_t)16 * 64 * 8 * 2);
    float*          ao32      = (float*)         alloc((size_t)2 * NC * 4);
    unsigned char*  h8        = (unsigned char*) alloc((size_t)N * 512);
    float*          s1s       = (float*)         alloc((size_t)N * 8 * 4);
    float*          s1d       = (float*)         alloc((size_t)N * 8 * 4);
    float*          h2p       = (float*)         alloc((size_t)N * 16 * 4);
    float*          s2s       = (float*)         alloc((size_t)N * 4);
    float*          s2d       = (float*)         alloc((size_t)N * 4);
    int*            row_start = (int*)           alloc((size_t)(N + 1) * 4);
    int*            csr_dst   = (int*)           alloc((size_t)E * 4);
    int*            pos_e     = (int*)           alloc((size_t)E * 4);
    int             nsb       = (N + 2047) / 2048;
    int*            bsum      = (int*)           alloc((size_t)nsb * 4);
    (void)ws_size;

    hipMemsetAsync(counts, 0, (size_t)N * 4, stream);

    // prep: weight conversions + histogram (dtype detected per-block from x sample)
    int bw = (H_HEADS * F_IN * D_HID) / 256;               // W frag blocks (512)
    int ba = bw + (H_HEADS * 2 * D_HID) / 256;             // + ah blocks (4)
    int bo = ba + (16 * 64 * 8) / 256;                     // + wob frag blocks (32); bo = ao block
    int nb = bo + 1 + (E + 255) / 256;                     // + hist blocks
    prep_kernel<<<nb, 256, 0, stream>>>(x_raw, Wh_raw, wh_f, ah_raw, ah32,
                                        Wo_raw, wob_f, ao_raw, ao32,
                                        esrc, counts, pos_e, N, E, bw, ba, bo);

    // hierarchical scan (2 dispatches)
    sum_kernel<<<nsb, 256, 0, stream>>>(counts, bsum, N);
    emit_kernel<<<nsb, 256, 0, stream>>>(counts, bsum, row_start, N, E);

    // fused layer-1 GEMM (blocks first) + scatter (after), one dispatch
    int nsc = (E + 255) / 256;
    int ngm = (N + 63) / 64;
    gemm1_scatter_kernel<<<ngm + nsc, 256, 0, stream>>>(x_raw, wh_f, ah32, h8, s1s, s1d,
                                                        esrc, edst, row_start, pos_e, csr_dst,
                                                        N, E, ngm);

    // layer-1 aggregation with MFMA-batched layer-2 projection
    edge_agg1_kernel<<<(N + 15) / 16, 256, 0, stream>>>(row_start, csr_dst, s1s, s1d,
                                                        h8, wob_f, ao32,
                                                        h2p, s2s, s2d, N);

    // layer-2 aggregation + log-softmax
    edge_agg2_kernel<<<(N + 3) / 4, 256, 0, stream>>>(row_start, csr_dst, h2p, s2s, s2d, d_out, x_raw, N);
}

// Round 12
// 280.023 us; speedup vs baseline: 1.0513x; 1.0046x over previous
//
#include <hip/hip_runtime.h>
#include <hip/hip_bf16.h>

#define F_IN    256
#define D_HID   64
#define H_HEADS 8
#define NC      10
#define ALPHA   0.2f

typedef __attribute__((ext_vector_type(8))) short short8;
typedef __attribute__((ext_vector_type(4))) float f32x4;
typedef __attribute__((ext_vector_type(2))) float f32x2;

// ---------- bf16 helpers ----------
__device__ __forceinline__ float bfu2f(unsigned short u) {
    union { float f; unsigned int i; } c; c.i = ((unsigned int)u) << 16; return c.f;
}
__device__ __forceinline__ unsigned short f2bfu(float f) {
    union { float f; unsigned int i; } c; c.f = f;
    unsigned int x = c.i;
    x += 0x7fffu + ((x >> 16) & 1u);   // round-to-nearest-even
    return (unsigned short)(x >> 16);
}

// ---------- inline dtype detection (f32 vs bf16 storage), wave-uniform ----------
// MUST run with ALL 64 lanes active (__ballot counts active lanes only).
__device__ __forceinline__ bool detect_f32(const void* xraw) {
    unsigned int w = ((const unsigned int*)xraw)[threadIdx.x & 63];
    unsigned int e = (w >> 7) & 0xffu;
    unsigned long long m = __ballot(e >= 140u);
    return __popcll(m) > 8;
}

// ---------- prep: weight conversions + edge histogram (+pos stash) ----------
__global__ __launch_bounds__(256) void prep_kernel(
    const void* __restrict__ x_raw,
    const void* __restrict__ Wh_raw, unsigned short* __restrict__ wh_f,
    const void* __restrict__ ah_raw, float* __restrict__ ah32,
    const void* __restrict__ Wo_raw, unsigned short* __restrict__ wob_f,
    const void* __restrict__ ao_raw, float* __restrict__ ao32,
    const int* __restrict__ esrc, int* __restrict__ counts, int* __restrict__ pos_e,
    int N, int E, int bw, int ba, int bo)
{
    int b = blockIdx.x;
    bool isf32 = detect_f32(x_raw);   // all lanes active here
    if (b < bw) {                       // W_heads [8][256][64] -> fragment-major bf16
        int i = b * 256 + threadIdx.x;
        int d = i & 63, k = (i >> 6) & 255, h = i >> 14;
        float v = isf32 ? ((const float*)Wh_raw)[i] : bfu2f(((const unsigned short*)Wh_raw)[i]);
        int ks = k >> 5, q = (k >> 3) & 3, j = k & 7;
        int c = d >> 4, m = d & 15;
        wh_f[(((h * 8 + ks) * 4 + c) << 9) + (q * 16 + m) * 8 + j] = f2bfu(v);
    } else if (b < ba) {                // a_heads -> f32 (1024)
        int i = (b - bw) * 256 + threadIdx.x;
        ah32[i] = isf32 ? ((const float*)ah_raw)[i] : bfu2f(((const unsigned short*)ah_raw)[i]);
    } else if (b < bo) {                // W_out [512,10] -> fragment-major bf16, cols padded to 16
        int i = (b - ba) * 256 + threadIdx.x;   // 0..8191 = (ks<<9) + L*8 + j
        int j = i & 7, L = (i >> 3) & 63, ks = i >> 9;
        int q = L >> 4, m = L & 15;
        int k = ks * 32 + q * 8 + j;
        float v = 0.f;
        if (m < NC)
            v = isf32 ? ((const float*)Wo_raw)[k * NC + m] : bfu2f(((const unsigned short*)Wo_raw)[k * NC + m]);
        wob_f[i] = f2bfu(v);
    } else if (b == bo) {               // a_out -> f32 (20)
        int i = threadIdx.x;
        if (i < 2 * NC)
            ao32[i] = isf32 ? ((const float*)ao_raw)[i] : bfu2f(((const unsigned short*)ao_raw)[i]);
    } else {                            // edge histogram + stash row-local position
        int e = (b - bo - 1) * 256 + threadIdx.x;
        if (e < E) {
            int s = esrc[e];
            int pos = atomicAdd(&counts[s], 1);
            pos_e[e] = pos;
        }
    }
}

// ---------- hierarchical CSR scan: 2 small parallel phases ----------
__global__ __launch_bounds__(256) void sum_kernel(
    const int* __restrict__ counts, int* __restrict__ bsum, int N)
{
    __shared__ int rs[256];
    int t = threadIdx.x;
    int base = blockIdx.x * 2048 + t * 8;
    int s = 0;
    if (base + 8 <= N) {
        int4 a = *(const int4*)(counts + base);
        int4 b = *(const int4*)(counts + base + 4);
        s = (a.x + a.y + a.z + a.w) + (b.x + b.y + b.z + b.w);
    } else {
        for (int k = 0; k < 8; ++k) if (base + k < N) s += counts[base + k];
    }
    rs[t] = s;
    __syncthreads();
    for (int off = 128; off > 0; off >>= 1) {
        if (t < off) rs[t] += rs[t + off];
        __syncthreads();
    }
    if (t == 0) bsum[blockIdx.x] = rs[0];
}

__global__ __launch_bounds__(256) void emit_kernel(
    const int* __restrict__ counts, const int* __restrict__ bsum,
    int* __restrict__ row_start, int N, int E)
{
    __shared__ int ts[256];
    int t = threadIdx.x;
    int goff = 0;
    for (int j = 0; j < blockIdx.x; ++j) goff += bsum[j];
    int base = blockIdx.x * 2048 + t * 8;
    int c[8];
    int tsum = 0;
    #pragma unroll
    for (int k = 0; k < 8; ++k) {
        c[k] = (base + k < N) ? counts[base + k] : 0;
        tsum += c[k];
    }
    ts[t] = tsum;
    __syncthreads();
    for (int off = 1; off < 256; off <<= 1) {
        int u = (t >= off) ? ts[t - off] : 0;
        __syncthreads();
        ts[t] += u;
        __syncthreads();
    }
    int run = goff + ts[t] - tsum;
    #pragma unroll
    for (int k = 0; k < 8; ++k) {
        if (base + k < N) { row_start[base + k] = run; run += c[k]; }
    }
    if (blockIdx.x == 0 && t == 0) row_start[N] = E;
}

// ---------- FUSED: layer-1 MFMA GEMM (blocks first, LDS-staged B) + scatter ----------
// Blocks [0, ngm): gemm1 — 8 heads/block, x_raw read directly, h stored FP8.
// Per head, the 32 KB B-panel is staged to LDS ONCE PER BLOCK (was: each of the
// 4 waves streaming it from L1/L2 redundantly = ~800 MB aggregate, the r9-r11
// latency/bandwidth wall). MFMAs then read conflict-free ds_read_b128.
// Blocks [ngm, ...): scatter (dispatched last so gemm waves start at t=0).
__global__ __launch_bounds__(256) void gemm1_scatter_kernel(
    const void* __restrict__ x_raw,            // [N,256] f32 or bf16
    const unsigned short* __restrict__ wh_f,   // fragment-major bf16
    const float* __restrict__ ah,              // [8,128] f32
    unsigned char* __restrict__ h8,            // [N,512] fp8 out
    float* __restrict__ s1s, float* __restrict__ s1d,
    const int* __restrict__ esrc, const int* __restrict__ edst,
    const int* __restrict__ row_start, const int* __restrict__ pos_e,
    int* __restrict__ csr_dst,
    int N, int E, int ngm)
{
    __shared__ unsigned short Bs[16384];       // 32 KB: one head's B panel
    __shared__ unsigned char Os8[64][80];      // fp8 staging, 80 B rows

    bool isf32 = detect_f32(x_raw);            // all lanes active (kernel entry)

    if (blockIdx.x >= ngm) {                   // ---- scatter part (block-uniform exit) ----
        int e = (blockIdx.x - ngm) * 256 + threadIdx.x;
        if (e < E) {
            int s = esrc[e];
            csr_dst[row_start[s] + pos_e[e]] = edst[e];
        }
        return;
    }

    // ---- gemm1 part: 64 rows x 8 heads ----
    const int t = threadIdx.x;
    const int w = t >> 6, lane = t & 63;
    const int q = lane >> 4, m = lane & 15;
    const int n0 = blockIdx.x * 64;

    int r = n0 + 16 * w + m;
    long rr = (long)(r < N ? r : N - 1);
    short8 afrag[8];
    if (isf32) {
        const float* xr = (const float*)x_raw + rr * 256;
        #pragma unroll
        for (int ks = 0; ks < 8; ++ks) {
            float4 f0 = *(const float4*)(xr + ks * 32 + q * 8);
            float4 f1 = *(const float4*)(xr + ks * 32 + q * 8 + 4);
            unsigned short u[8];
            u[0] = f2bfu(f0.x); u[1] = f2bfu(f0.y); u[2] = f2bfu(f0.z); u[3] = f2bfu(f0.w);
            u[4] = f2bfu(f1.x); u[5] = f2bfu(f1.y); u[6] = f2bfu(f1.z); u[7] = f2bfu(f1.w);
            afrag[ks] = *(const short8*)u;
        }
    } else {
        const unsigned short* xr = (const unsigned short*)x_raw + rr * 256;
        #pragma unroll
        for (int ks = 0; ks < 8; ++ks)
            afrag[ks] = *(const short8*)(xr + ks * 32 + q * 8);
    }

    #pragma unroll 1
    for (int h = 0; h < 8; ++h) {
        // stage this head's 32 KB B panel: one copy per BLOCK (coalesced uint4)
        __syncthreads();                       // prior head's Bs reads drained
        {
            const uint4* src = (const uint4*)(wh_f + (((long)h * 32) << 9));
            uint4* dst = (uint4*)Bs;
            #pragma unroll
            for (int rr2 = 0; rr2 < 8; ++rr2)
                dst[rr2 * 256 + t] = src[rr2 * 256 + t];
        }
        __syncthreads();                       // Bs ready for all waves

        f32x4 acc[4] = {};
        #pragma unroll
        for (int ks = 0; ks < 8; ++ks) {
            #pragma unroll
            for (int c = 0; c < 4; ++c) {
                short8 b = *(const short8*)&Bs[(((ks * 4 + c) << 9)) + lane * 8];
                acc[c] = __builtin_amdgcn_mfma_f32_16x16x32_bf16(afrag[ks], b, acc[c], 0, 0, 0);
            }
        }

        const float* a1 = ah + h * 128;
        float a1m = a1[m], a1m16 = a1[16 + m], a1m32 = a1[32 + m], a1m48 = a1[48 + m];
        float a2m = a1[64 + m], a2m16 = a1[80 + m], a2m32 = a1[96 + m], a2m48 = a1[112 + m];
        #pragma unroll
        for (int reg = 0; reg < 4; ++reg) {
            float p1 = acc[0][reg] * a1m + acc[1][reg] * a1m16 + acc[2][reg] * a1m32 + acc[3][reg] * a1m48;
            float p2 = acc[0][reg] * a2m + acc[1][reg] * a2m16 + acc[2][reg] * a2m32 + acc[3][reg] * a2m48;
            #pragma unroll
            for (int off = 1; off < 16; off <<= 1) {
                p1 += __shfl_xor(p1, off);
                p2 += __shfl_xor(p2, off);
            }
            int row = n0 + 16 * w + q * 4 + reg;
            if (m == 0 && row < N) {
                s1s[row * 8 + h] = p1;
                s1d[row * 8 + h] = p2;
            }
        }

        // pack f32 -> fp8 pairs via lane-pair shuffle (even m packs dims m,m+1)
        #pragma unroll
        for (int c = 0; c < 4; ++c) {
            #pragma unroll
            for (int reg = 0; reg < 4; ++reg) {
                float a = acc[c][reg];
                float b = __shfl_xor(a, 1);
                if (!(m & 1)) {
                    unsigned int p = __builtin_amdgcn_cvt_pk_fp8_f32(a, b, 0u, false);
                    *(unsigned short*)&Os8[16 * w + q * 4 + reg][c * 16 + m] = (unsigned short)(p & 0xffffu);
                }
            }
        }
        // writeback: 16 rows x 64 B per wave per head
        {
            int row = lane >> 2, q4 = lane & 3;
            int rr2 = n0 + 16 * w + row;
            if (rr2 < N)
                *(uint4*)(h8 + (long)rr2 * 512 + h * 64 + q4 * 16) =
                    *(const uint4*)&Os8[16 * w + row][q4 * 16];
        }
    }
}

// ---------- layer-1 CSR gather (fp8 payload) + MFMA-batched layer-2 projection ----------
__device__ __forceinline__ void accpk(f32x2& a01, f32x2& a23, f32x2& a45, f32x2& a67,
                                      float ev, uint2 v) {
    f32x2 e = {ev, ev};
    a01 += e * __builtin_amdgcn_cvt_pk_f32_fp8(v.x, false);
    a23 += e * __builtin_amdgcn_cvt_pk_f32_fp8(v.x, true);
    a45 += e * __builtin_amdgcn_cvt_pk_f32_fp8(v.y, false);
    a67 += e * __builtin_amdgcn_cvt_pk_f32_fp8(v.y, true);
}

__global__ __launch_bounds__(256) void edge_agg1_kernel(
    const int* __restrict__ row_start, const int* __restrict__ csr_dst,
    const float* __restrict__ s1s, const float* __restrict__ s1d,
    const unsigned char* __restrict__ h8,      // [N,512] fp8
    const unsigned short* __restrict__ wob,    // [16][64][8] bf16 frag-major (Wo)
    const float* __restrict__ ao,              // [20] f32
    float* __restrict__ h2p,                   // [N,16] f32, pad=0
    float* __restrict__ s2s, float* __restrict__ s2d,
    int N)
{
    __shared__ unsigned short X[16][520];      // [node][dim] bf16, +8 pad

    int lane = threadIdx.x & 63;
    int wv = threadIdx.x >> 6;
    int n0 = blockIdx.x * 16;
    int h = lane >> 3;
    const unsigned lo8 = (unsigned)lane << 3;  // byte offset of this lane's 8 dims
    const unsigned h4  = (unsigned)h << 2;     // byte offset into s1d row
    const char* __restrict__ s1db = (const char*)s1d;

    #pragma unroll 1
    for (int nl = 0; nl < 4; ++nl) {
        int nloc = wv * 4 + nl;
        int n = n0 + nloc;
        if (n >= N) continue;
        int beg = row_start[n], end = row_start[n + 1];
        float ss = s1s[n * 8 + h];

        f32x2 a01 = {0.f, 0.f}, a23 = {0.f, 0.f}, a45 = {0.f, 0.f}, a67 = {0.f, 0.f};
        float rs = 0.f;
        int i = beg;
        for (; i + 4 <= end; i += 4) {
            int d0 = csr_dst[i], d1 = csr_dst[i + 1], d2 = csr_dst[i + 2], d3 = csr_dst[i + 3];
            float sd0 = *(const float*)(s1db + ((((unsigned)d0) << 5) | h4));
            float sd1 = *(const float*)(s1db + ((((unsigned)d1) << 5) | h4));
            float sd2 = *(const float*)(s1db + ((((unsigned)d2) << 5) | h4));
            float sd3 = *(const float*)(s1db + ((((unsigned)d3) << 5) | h4));
            uint2 w0 = *(const uint2*)(h8 + ((((unsigned)d0) << 9) | lo8));
            uint2 w1 = *(const uint2*)(h8 + ((((unsigned)d1) << 9) | lo8));
            uint2 w2 = *(const uint2*)(h8 + ((((unsigned)d2) << 9) | lo8));
            uint2 w3 = *(const uint2*)(h8 + ((((unsigned)d3) << 9) | lo8));
            float sc0 = ss + sd0, sc1 = ss + sd1, sc2 = ss + sd2, sc3 = ss + sd3;
            float ev0 = __expf(-fmaxf(sc0, ALPHA * sc0));
            float ev1 = __expf(-fmaxf(sc1, ALPHA * sc1));
            float ev2 = __expf(-fmaxf(sc2, ALPHA * sc2));
            float ev3 = __expf(-fmaxf(sc3, ALPHA * sc3));
            rs += (ev0 + ev1) + (ev2 + ev3);
            accpk(a01, a23, a45, a67, ev0, w0);
            accpk(a01, a23, a45, a67, ev1, w1);
            accpk(a01, a23, a45, a67, ev2, w2);
            accpk(a01, a23, a45, a67, ev3, w3);
        }
        for (; i < end; ++i) {
            int d = csr_dst[i];
            float sd = *(const float*)(s1db + ((((unsigned)d) << 5) | h4));
            uint2 wv4 = *(const uint2*)(h8 + ((((unsigned)d) << 9) | lo8));
            float sc = ss + sd;
            float ev = __expf(-fmaxf(sc, ALPHA * sc));
            rs += ev;
            accpk(a01, a23, a45, a67, ev, wv4);
        }
        float inv = 1.f / rs;
        float accs[8] = {a01.x, a01.y, a23.x, a23.y, a45.x, a45.y, a67.x, a67.y};
        unsigned short o[8];
        #pragma unroll
        for (int j = 0; j < 8; ++j) {
            float v = accs[j] * inv;
            v = v > 0.f ? v : __expf(v) - 1.f;   // elu -> xcat element (bf16)
            o[j] = f2bfu(v);
        }
        *(uint4*)&X[nloc][lane * 8] = *(const uint4*)o;
    }
    __syncthreads();

    if (wv == 0) {
        const int q = lane >> 4, m = lane & 15;
        f32x4 pacc = {};
        #pragma unroll
        for (int ks = 0; ks < 16; ++ks) {
            short8 a = *(const short8*)&X[m][ks * 32 + q * 8];
            short8 b = *(const short8*)(wob + (ks << 9) + lane * 8);
            pacc = __builtin_amdgcn_mfma_f32_16x16x32_bf16(a, b, pacc, 0, 0, 0);
        }
        float a1m = (m < NC) ? ao[m] : 0.f;
        float a2m = (m < NC) ? ao[NC + m] : 0.f;
        #pragma unroll
        for (int reg = 0; reg < 4; ++reg) {
            int n = n0 + q * 4 + reg;           // C row = local node
            float pv = pacc[reg];                // C col = class m (0 for m>=NC)
            if (n < N) h2p[(long)n * 16 + m] = pv;
            float p1 = pv * a1m, p2 = pv * a2m;
            #pragma unroll
            for (int off = 1; off < 16; off <<= 1) {
                p1 += __shfl_xor(p1, off);
                p2 += __shfl_xor(p2, off);
            }
            if (m == 0 && n < N) { s2s[n] = p1; s2d[n] = p2; }
        }
    }
}

// ---------- layer-2 CSR gather v2: wave/node, 8 edge slots x 8 dim-lanes ----------
__global__ __launch_bounds__(256) void edge_agg2_kernel(
    const int* __restrict__ row_start, const int* __restrict__ csr_dst,
    const float* __restrict__ h2p,             // [N,16] f32, pad=0
    const float* __restrict__ s_src2, const float* __restrict__ s_dst2,
    void* __restrict__ out, const void* __restrict__ x_raw, int N)
{
    bool isf32 = detect_f32(x_raw);   // all lanes active
    int lane = threadIdx.x & 63;
    int n = blockIdx.x * 4 + (threadIdx.x >> 6);
    if (n >= N) return;
    int c2 = lane & 7, j = lane >> 3;   // 8 edge slots x 8 class-pairs
    int beg = row_start[n], end = row_start[n + 1];
    float ss = s_src2[n];
    const char* __restrict__ h2b = (const char*)h2p;
    const char* __restrict__ sdb = (const char*)s_dst2;
    const unsigned c8 = (unsigned)c2 << 3;
    float rs = 0.f, a0 = 0.f, a1 = 0.f;
    for (int i0 = beg; i0 < end; i0 += 8) {
        int i = i0 + j;
        if (i < end) {
            int d = csr_dst[i];
            float sdv = *(const float*)(sdb + (((unsigned)d) << 2));
            float sc = ss + sdv;
            float ev = __expf(-fmaxf(sc, ALPHA * sc));
            rs += ev;
            float2 hv = *(const float2*)(h2b + ((((unsigned)d) << 6) | c8));
            a0 += ev * hv.x;
            a1 += ev * hv.y;
        }
    }
    rs += __shfl_xor(rs, 8);  rs += __shfl_xor(rs, 16);  rs += __shfl_xor(rs, 32);
    a0 += __shfl_xor(a0, 8);  a0 += __shfl_xor(a0, 16);  a0 += __shfl_xor(a0, 32);
    a1 += __shfl_xor(a1, 8);  a1 += __shfl_xor(a1, 16);  a1 += __shfl_xor(a1, 32);
    float inv = 1.f / rs;
    float v0 = a0 * inv, v1 = a1 * inv;
    v0 = v0 > 0.f ? v0 : __expf(v0) - 1.f;       // elu
    v1 = v1 > 0.f ? v1 : __expf(v1) - 1.f;
    // log-softmax over the 10 valid classes (c2<5 holds valid pairs)
    bool valid = (c2 * 2 + 1 < NC);
    float vm = valid ? fmaxf(v0, v1) : -1e30f;
    #pragma unroll
    for (int off = 1; off < 8; off <<= 1) vm = fmaxf(vm, __shfl_xor(vm, off, 64));
    float ex = valid ? (__expf(v0 - vm) + __expf(v1 - vm)) : 0.f;
    #pragma unroll
    for (int off = 1; off < 8; off <<= 1) ex += __shfl_xor(ex, off, 64);
    float lse = vm + logf(ex);
    if (valid && j == 0) {
        if (isf32) {
            *(float2*)((float*)out + (long)n * NC + c2 * 2) = make_float2(v0 - lse, v1 - lse);
        } else {
            unsigned int o = (unsigned int)f2bfu(v0 - lse) | ((unsigned int)f2bfu(v1 - lse) << 16);
            *(unsigned int*)((unsigned short*)out + (long)n * NC + c2 * 2) = o;
        }
    }
}

extern "C" void kernel_launch(void* const* d_in, const int* in_sizes, int n_in,
                              void* d_out, int out_size, void* d_ws, size_t ws_size,
                              hipStream_t stream)
{
    const void* x_raw  = d_in[0];
    const int*  esrc   = (const int*)d_in[1];
    const int*  edst   = (const int*)d_in[2];
    const void* Wh_raw = d_in[3];
    const void* ah_raw = d_in[4];
    const void* Wo_raw = d_in[5];
    const void* ao_raw = d_in[6];

    const int N = in_sizes[0] / F_IN;
    const int E = in_sizes[1];

    char* ws = (char*)d_ws;
    size_t off = 0;
    auto alloc = [&](size_t bytes) -> void* {
        void* p = ws + off;
        off = (off + bytes + 255) & ~(size_t)255;
        return p;
    };
    // zero-init region first (counts only -> ONE memset)
    int*            counts    = (int*)           alloc((size_t)N * 4);

    unsigned short* wh_f      = (unsigned short*)alloc((size_t)H_HEADS * D_HID * F_IN * 2);
    float*          ah32      = (float*)         alloc((size_t)H_HEADS * 2 * D_HID * 4);
    unsigned short* wob_f     = (unsigned short*)alloc((size_t)16 * 64 * 8 * 2);
    float*          ao32      = (float*)         alloc((size_t)2 * NC * 4);
    unsigned char*  h8        = (unsigned char*) alloc((size_t)N * 512);
    float*          s1s       = (float*)         alloc((size_t)N * 8 * 4);
    float*          s1d       = (float*)         alloc((size_t)N * 8 * 4);
    float*          h2p       = (float*)         alloc((size_t)N * 16 * 4);
    float*          s2s       = (float*)         alloc((size_t)N * 4);
    float*          s2d       = (float*)         alloc((size_t)N * 4);
    int*            row_start = (int*)           alloc((size_t)(N + 1) * 4);
    int*            csr_dst   = (int*)           alloc((size_t)E * 4);
    int*            pos_e     = (int*)           alloc((size_t)E * 4);
    int             nsb       = (N + 2047) / 2048;
    int*            bsum      = (int*)           alloc((size_t)nsb * 4);
    (void)ws_size;

    hipMemsetAsync(counts, 0, (size_t)N * 4, stream);

    // prep: weight conversions + histogram (dtype detected per-block from x sample)
    int bw = (H_HEADS * F_IN * D_HID) / 256;               // W frag blocks (512)
    int ba = bw + (H_HEADS * 2 * D_HID) / 256;             // + ah blocks (4)
    int bo = ba + (16 * 64 * 8) / 256;                     // + wob frag blocks (32); bo = ao block
    int nb = bo + 1 + (E + 255) / 256;                     // + hist blocks
    prep_kernel<<<nb, 256, 0, stream>>>(x_raw, Wh_raw, wh_f, ah_raw, ah32,
                                        Wo_raw, wob_f, ao_raw, ao32,
                                        esrc, counts, pos_e, N, E, bw, ba, bo);

    // hierarchical scan (2 dispatches)
    sum_kernel<<<nsb, 256, 0, stream>>>(counts, bsum, N);
    emit_kernel<<<nsb, 256, 0, stream>>>(counts, bsum, row_start, N, E);

    // fused layer-1 GEMM (blocks first, LDS-staged B) + scatter (after), one dispatch
    int nsc = (E + 255) / 256;
    int ngm = (N + 63) / 64;
    gemm1_scatter_kernel<<<ngm + nsc, 256, 0, stream>>>(x_raw, wh_f, ah32, h8, s1s, s1d,
                                                        esrc, edst, row_start, pos_e, csr_dst,
                                                        N, E, ngm);

    // layer-1 aggregation with MFMA-batched layer-2 projection
    edge_agg1_kernel<<<(N + 15) / 16, 256, 0, stream>>>(row_start, csr_dst, s1s, s1d,
                                                        h8, wob_f, ao32,
                                                        h2p, s2s, s2d, N);

    // layer-2 aggregation + log-softmax
    edge_agg2_kernel<<<(N + 3) / 4, 256, 0, stream>>>(row_start, csr_dst, h2p, s2s, s2d, d_out, x_raw, N);
}